// Round 5
// baseline (9329.775 us; speedup 1.0000x reference)
//
#include <hip/hip_runtime.h>
#include <stdint.h>

#define L_ 512
#define TPB 1024
#define NBUF (L_ * L_)

// ---------------------------------------------------------------------------
// pair_mask dtype probe (single block, self-initializing, deterministic).
//   bit0: some u32 word > 1                -> not int32 0/1
//   bit1: some byte not in {0,1}           -> not uint8 0/1
//   bit2: some u16 half not in {0,0x3F80}  -> not bf16 0/1
//   bit3: word 0x3F803F80 / 0x00003F80     -> bf16-only pattern (impossible f32)
//   bit4: some u16 half not in {0,0x3C00}  -> not f16 0/1
// ---------------------------------------------------------------------------
__global__ __launch_bounds__(1024) void fd_mask_probe(const unsigned int* __restrict__ pm,
                                                      int n32,
                                                      unsigned int* __restrict__ flags) {
    __shared__ unsigned int sf;
    if (threadIdx.x == 0) sf = 0u;
    __syncthreads();
    unsigned int local = 0;
    const int nscan = n32 < 65536 ? n32 : 65536;
    for (int idx = threadIdx.x; idx < nscan; idx += 1024) {
        const unsigned int w = pm[idx];
        const unsigned int h0 = w & 0xFFFFu, h1 = w >> 16;
        if (w > 1u) local |= 1u;
        if (w & 0xFEFEFEFEu) local |= 2u;
        if ((h0 != 0u && h0 != 0x3F80u) || (h1 != 0u && h1 != 0x3F80u)) local |= 4u;
        if (w == 0x3F803F80u || w == 0x00003F80u) local |= 8u;
        if ((h0 != 0u && h0 != 0x3C00u) || (h1 != 0u && h1 != 0x3C00u)) local |= 16u;
    }
    if (local) atomicOr(&sf, local);
    __syncthreads();
    if (threadIdx.x == 0) flags[0] = sf;
}

// ---------------------------------------------------------------------------
// Nussinov DP (f32, exact JAX-reference semantics) + backtrace.
// One block per batch, span wavefront, dp kept row-major AND transposed so
// dp[k+1][j] is a contiguous row read. Lex (value,t) shuffle-min == numpy
// first-occurrence argmin. Output: -1 unpaired, partner index 0-based.
// BUGFIX r5: pair_mask views are now offset by batch (r1-r4 read batch 0's
// mask for every batch -> batches 1..15 paired wrong -> absmax 513).
// ---------------------------------------------------------------------------
__global__ __launch_bounds__(TPB) void fd_nussinov(
    const float* __restrict__ e_pair, const float* __restrict__ e_unp,
    const unsigned int* __restrict__ pm, const unsigned int* __restrict__ flags,
    int* __restrict__ out, float* __restrict__ dp_ws, float* __restrict__ dpT_ws,
    unsigned short* __restrict__ ptr_ws)
{
    const int b = blockIdx.x;
    const int tid = threadIdx.x;
    const float* ep  = e_pair + (size_t)b * NBUF;
    const float* eun = e_unp  + (size_t)b * L_;
    float* dp  = dp_ws  + (size_t)b * NBUF;
    float* dpT = dpT_ws + (size_t)b * NBUF;
    unsigned short* ptr = ptr_ws + (size_t)b * NBUF;
    int* res = out + (size_t)b * L_;

    // mask dtype dispatch (uniform branch) — ALL views batch-offset.
    const unsigned int f = flags[0];
    int mode;
    if (!(f & 1u))      mode = 0;                       // int32 0/1
    else if (!(f & 2u)) mode = 1;                       // uint8 0/1
    else if (!(f & 4u)) mode = (f & 8u) ? 3 : 2;        // bf16 vs f32
    else                mode = (!(f & 16u)) ? 3 : 2;    // f16 else f32 fallback
    const unsigned int*   pmW  = pm + (size_t)b * NBUF;
    const unsigned char*  pm8  = ((const unsigned char*) pm) + (size_t)b * NBUF;
    const unsigned short* pm16 = ((const unsigned short*)pm) + (size_t)b * NBUF;
    const float*          pmf  = ((const float*)         pm) + (size_t)b * NBUF;

    __shared__ float eu[L_];
    __shared__ int sti[2 * L_];
    __shared__ int stj[2 * L_];

    if (tid < L_) eu[tid] = eun[tid];
    __syncthreads();
    if (tid < L_) {
        dp [(size_t)tid * L_ + tid] = eu[tid];
        dpT[(size_t)tid * L_ + tid] = eu[tid];
    }
    __syncthreads();

    for (int s = 2; s <= L_; ++s) {
        const int C = L_ - s + 1;             // cells this span
        int G = 1;                            // lanes/cell: largest pow2, G*C<=TPB, <=64
        while (G < 64 && (G * 2 * C) <= TPB) G <<= 1;
        const int lane = tid & (G - 1);
        const int c = tid / G;
        const int tmax = s - 2;
        if (c < C) {
            const int i = c, j = c + s - 1;
            const float* pA = dp  + (size_t)i * L_ + i;      // dp[i][i+t]
            const float* pB = dpT + (size_t)j * L_ + i + 1;  // dp[i+t+1][j]
            float minv = 3.0e38f;
            int   mint = 0;
            for (int t = lane; t <= tmax; t += G) {          // ascending t per lane
                const float v = pA[t] + pB[t];
                if (v < minv) { minv = v; mint = t; }        // strict <: earliest t
            }
            for (int off = G >> 1; off > 0; off >>= 1) {     // lex (v,t) min merge
                const float ov = __shfl_xor(minv, off, G);
                const int   ot = __shfl_xor(mint, off, G);
                if (ov < minv || (ov == minv && ot < mint)) { minv = ov; mint = ot; }
            }
            if (lane == 0) {
                const float c0 = pB[0]    + eu[i];           // dp[i+1][j] + e_unp[i]
                const float c1 = pA[tmax] + eu[j];           // dp[i][j-1] + e_unp[j]
                const float inner = (s >= 3) ? dp[(size_t)(i + 1) * L_ + (j - 1)] : 0.0f;
                const size_t midx = (size_t)i * L_ + j;
                const float c2 = inner + ep[midx];
                bool mbit;
                if (mode == 0)      mbit = pmW[midx]  != 0u;
                else if (mode == 1) mbit = pm8[midx]  != 0;
                else if (mode == 3) mbit = pm16[midx] != 0;
                else                mbit = pmf[midx]  != 0.0f;
                const bool pok = mbit && ((j - i) > 4);      // min_hairpin = 4
                float best = c0; int bp = 0;
                if (c1 < best)          { best = c1;   bp = 1; }
                if (pok && (c2 < best)) { best = c2;   bp = 2; }
                if (minv < best)        { best = minv; bp = i + mint + 3; }
                dp [(size_t)i * L_ + j] = best;
                dpT[(size_t)j * L_ + i] = best;
                ptr[midx] = (unsigned short)bp;
            }
        }
        __syncthreads();
    }

    // result init (-1 = unpaired, 0-based partners) then serial backtrace.
    for (int idx = tid; idx < L_; idx += TPB) res[idx] = -1;
    __syncthreads();
    if (tid == 0) {
        int sp = 1;
        sti[0] = 0; stj[0] = L_ - 1;
        while (sp > 0) {
            --sp;
            const int i = sti[sp], j = stj[sp];
            if (i < j) {
                const int p = (int)ptr[(size_t)i * L_ + j];
                if (p == 0)      { sti[sp] = i + 1; stj[sp] = j;     ++sp; }
                else if (p == 1) { sti[sp] = i;     stj[sp] = j - 1; ++sp; }
                else if (p == 2) {
                    res[i] = j; res[j] = i;
                    if (i + 1 <= j - 1) { sti[sp] = i + 1; stj[sp] = j - 1; ++sp; }
                } else {
                    const int k = p - 3;
                    sti[sp] = i;     stj[sp] = k; ++sp;   // pushed first
                    sti[sp] = k + 1; stj[sp] = j; ++sp;   // popped first (matches ref)
                }
            }
        }
    }
}

extern "C" void kernel_launch(void* const* d_in, const int* in_sizes, int n_in,
                              void* d_out, int out_size, void* d_ws, size_t ws_size,
                              hipStream_t stream) {
    const float* e_pair = (const float*)d_in[0];
    const float* e_unp  = (const float*)d_in[1];
    const unsigned int* pm = (const unsigned int*)d_in[2];
    const int B = in_sizes[1] / L_;          // e_unp is (B, L)
    int* out = (int*)d_out;

    // ws layout: [flags: 256B] [dp: B*L*L f32] [dpT: B*L*L f32] [ptr: B*L*L u16]
    unsigned int* flags = (unsigned int*)d_ws;
    float* dp_ws  = (float*)((char*)d_ws + 256);
    float* dpT_ws = dp_ws + (size_t)B * NBUF;
    unsigned short* ptr_ws = (unsigned short*)(dpT_ws + (size_t)B * NBUF);

    const int n32 = in_sizes[2] / 4;         // safe prefix for all dtype layouts
    fd_mask_probe<<<dim3(1), dim3(1024), 0, stream>>>(pm, n32, flags);
    fd_nussinov<<<dim3(B), dim3(TPB), 0, stream>>>(e_pair, e_unp, pm, flags, out,
                                                   dp_ws, dpT_ws, ptr_ws);
}

// Round 6
// 2254.440 us; speedup vs baseline: 4.1384x; 4.1384x over previous
//
#include <hip/hip_runtime.h>
#include <stdint.h>

#define L_ 512
#define NBUF (L_ * L_)
#define T_ 64
#define NT_ 8
#define INFV 3.0e38f

// ---------------------------------------------------------------------------
// pair_mask dtype probe (unchanged from r5 — verified working).
// ---------------------------------------------------------------------------
__global__ __launch_bounds__(1024) void fd_mask_probe(const unsigned int* __restrict__ pm,
                                                      int n32,
                                                      unsigned int* __restrict__ flags) {
    __shared__ unsigned int sf;
    if (threadIdx.x == 0) sf = 0u;
    __syncthreads();
    unsigned int local = 0;
    const int nscan = n32 < 65536 ? n32 : 65536;
    for (int idx = threadIdx.x; idx < nscan; idx += 1024) {
        const unsigned int w = pm[idx];
        const unsigned int h0 = w & 0xFFFFu, h1 = w >> 16;
        if (w > 1u) local |= 1u;
        if (w & 0xFEFEFEFEu) local |= 2u;
        if ((h0 != 0u && h0 != 0x3F80u) || (h1 != 0u && h1 != 0x3F80u)) local |= 4u;
        if (w == 0x3F803F80u || w == 0x00003F80u) local |= 8u;
        if ((h0 != 0u && h0 != 0x3C00u) || (h1 != 0u && h1 != 0x3C00u)) local |= 16u;
    }
    if (local) atomicOr(&sf, local);
    __syncthreads();
    if (threadIdx.x == 0) flags[0] = sf;
}

__device__ __forceinline__ int mask_mode(unsigned int f) {
    if (!(f & 1u)) return 0;                 // int32 0/1
    if (!(f & 2u)) return 1;                 // uint8 0/1
    if (!(f & 4u)) return (f & 8u) ? 3 : 2;  // bf16 vs f32
    return (!(f & 16u)) ? 3 : 2;             // f16 else f32
}

__device__ __forceinline__ bool mask_bit(int mode, const unsigned int* pmW,
                                         const unsigned char* pm8,
                                         const unsigned short* pm16,
                                         const float* pmf, size_t gi) {
    if (mode == 0) return pmW[gi] != 0u;
    if (mode == 1) return pm8[gi] != 0;
    if (mode == 3) return pm16[gi] != 0;
    return pmf[gi] != 0.0f;
}

// ---------------------------------------------------------------------------
// Diagonal tiles (d=0): triangular 64x64 DP fully in LDS. 63 wavefront steps.
// ---------------------------------------------------------------------------
__global__ __launch_bounds__(256) void fd_diag(
    const float* __restrict__ e_pair, const float* __restrict__ e_unp,
    const unsigned int* __restrict__ pm, const unsigned int* __restrict__ flags,
    float* __restrict__ dp_ws, unsigned short* __restrict__ ptr_ws)
{
    const int b = blockIdx.x / NT_;
    const int I = blockIdx.x % NT_;
    const int t = threadIdx.x;
    const int r0 = I * T_;
    const float* ep = e_pair + (size_t)b * NBUF;
    float* dp = dp_ws + (size_t)b * NBUF;
    unsigned short* ptr = ptr_ws + (size_t)b * NBUF;
    const int mode = mask_mode(flags[0]);
    const unsigned int*   pmW  = pm + (size_t)b * NBUF;
    const unsigned char*  pm8  = ((const unsigned char*) pm) + (size_t)b * NBUF;
    const unsigned short* pm16 = ((const unsigned short*)pm) + (size_t)b * NBUF;
    const float*          pmf  = ((const float*)         pm) + (size_t)b * NBUF;

    __shared__ float Ct[T_][T_ + 4];
    __shared__ float epl[T_][T_ + 4];
    __shared__ unsigned char mkb[T_][T_ + 4];
    __shared__ unsigned short bp[T_][T_ + 4];
    __shared__ float eu[T_];

    for (int e = t; e < T_ * T_; e += 256) {
        const int r = e >> 6, c = e & 63;
        const size_t gi = (size_t)(r0 + r) * L_ + r0 + c;
        epl[r][c] = ep[gi];
        mkb[r][c] = mask_bit(mode, pmW, pm8, pm16, pmf, gi) ? 1 : 0;
    }
    if (t < T_) eu[t] = e_unp[(size_t)b * L_ + r0 + t];
    __syncthreads();
    if (t < T_) Ct[t][t] = eu[t];
    __syncthreads();

    const int cell = t >> 2, sub = t & 3;
    for (int m = 1; m < T_; ++m) {
        if (cell < T_ - m) {
            const int ti = cell, tj = cell + m;
            float mv = INFV; int km = 0;
            for (int tk = ti + sub; tk < tj; tk += 4) {   // ascending k, strict <
                const float v = Ct[ti][tk] + Ct[tk + 1][tj];
                if (v < mv) { mv = v; km = tk; }
            }
            for (int off = 1; off < 4; off <<= 1) {       // lex (v,k) reduce
                const float ov = __shfl_xor(mv, off, 4);
                const int   ok = __shfl_xor(km, off, 4);
                if (ov < mv || (ov == mv && ok < km)) { mv = ov; km = ok; }
            }
            if (sub == 0) {
                const float c0 = Ct[ti + 1][tj] + eu[ti];
                const float c1 = Ct[ti][tj - 1] + eu[tj];
                const float inner = (m >= 2) ? Ct[ti + 1][tj - 1] : 0.0f;
                const float c2 = inner + epl[ti][tj];
                const bool pok = mkb[ti][tj] && (m > 4);
                float best = c0; int bv = 0;
                if (c1 < best)        { best = c1; bv = 1; }
                if (pok && c2 < best) { best = c2; bv = 2; }
                if (mv < best)        { best = mv; bv = r0 + km + 3; }
                Ct[ti][tj] = best;
                bp[ti][tj] = (unsigned short)bv;
            }
        }
        __syncthreads();
    }
    for (int e = t; e < T_ * T_; e += 256) {
        const int r = e >> 6, c = e & 63;
        if (c >= r) {
            const size_t gi = (size_t)(r0 + r) * L_ + r0 + c;
            dp[gi] = Ct[r][c];
            if (c > r) ptr[gi] = bp[r][c];
        }
    }
}

// ---------------------------------------------------------------------------
// Off-diagonal tile step (d>=1). Bulk lex-min-plus over interior k blocks
// (4x4 register tiles, LDS-staged, ascending k) then 127-step intra-tile
// wavefront (left/right k parts + c0/c1/c2) fully in LDS.
// do_bt: fused backtrace on the final step (tile (0,NT-1) per batch).
// ---------------------------------------------------------------------------
__global__ __launch_bounds__(256) void fd_step(
    const float* __restrict__ e_pair, const float* __restrict__ e_unp,
    const unsigned int* __restrict__ pm, const unsigned int* __restrict__ flags,
    float* __restrict__ dp_ws, unsigned short* __restrict__ ptr_ws,
    int* __restrict__ out, int d, int nI, int do_bt)
{
    const int b = blockIdx.x / nI;
    const int I = blockIdx.x % nI;
    const int J = I + d;
    const int t = threadIdx.x;
    const int r0 = I * T_, q0 = J * T_;
    const float* ep = e_pair + (size_t)b * NBUF;
    float* dp = dp_ws + (size_t)b * NBUF;
    unsigned short* ptr = ptr_ws + (size_t)b * NBUF;
    const int mode = mask_mode(flags[0]);
    const unsigned int*   pmW  = pm + (size_t)b * NBUF;
    const unsigned char*  pm8  = ((const unsigned char*) pm) + (size_t)b * NBUF;
    const unsigned short* pm16 = ((const unsigned short*)pm) + (size_t)b * NBUF;
    const float*          pmf  = ((const float*)         pm) + (size_t)b * NBUF;

    __shared__ float SA[T_][T_ + 4];        // bulk A chunk, then tile (I,I)
    __shared__ float SB[T_][T_ + 4];        // bulk B chunk, then tile (J,J)
    __shared__ float Ct[T_][T_ + 4];        // the tile being computed
    __shared__ float accv[T_][T_ + 4];      // bulk lex-min value
    __shared__ unsigned short acck[T_][T_ + 4]; // bulk lex-min k (global, <512)
    __shared__ float epl[T_][T_ + 4];
    __shared__ unsigned char mkb[T_][T_ + 4];
    __shared__ unsigned short bp[T_][T_ + 4];
    __shared__ float euI[T_], euJ[T_], rowB[T_], colL[T_];
    __shared__ float cornerS;
    __shared__ int sti[2 * L_], stj[2 * L_];

    // ---- bulk: k in [(I+1)*T, J*T) over interior blocks K ----
    float av[16]; int akr[16];
    const int ti0 = (t >> 4) * 4, tj0 = (t & 15) * 4;
#pragma unroll
    for (int q = 0; q < 16; ++q) { av[q] = INFV; akr[q] = 0; }
    for (int K = I + 1; K < J; ++K) {
        const int kb = K * T_;
        __syncthreads();
        for (int e = t; e < T_ * T_; e += 256) {
            const int r = e >> 6, c = e & 63;
            SA[r][c] = dp[(size_t)(r0 + r) * L_ + kb + c];       // dp[i][k]
            SB[r][c] = dp[(size_t)(kb + 1 + r) * L_ + q0 + c];   // dp[k+1][j]
        }
        __syncthreads();
        for (int kk = 0; kk < T_; ++kk) {
            float a[4], bb[4];
#pragma unroll
            for (int r = 0; r < 4; ++r) a[r] = SA[ti0 + r][kk];
#pragma unroll
            for (int c = 0; c < 4; ++c) bb[c] = SB[kk][tj0 + c];
            const int kg = kb + kk;
#pragma unroll
            for (int r = 0; r < 4; ++r)
#pragma unroll
                for (int c = 0; c < 4; ++c) {
                    const float v = a[r] + bb[c];
                    const int q = r * 4 + c;
                    if (v < av[q]) { av[q] = v; akr[q] = kg; }   // ascending k
                }
        }
    }
    __syncthreads();
#pragma unroll
    for (int r = 0; r < 4; ++r)
#pragma unroll
        for (int c = 0; c < 4; ++c) {
            accv[ti0 + r][tj0 + c] = av[r * 4 + c];
            acck[ti0 + r][tj0 + c] = (unsigned short)akr[r * 4 + c];
        }

    // ---- stage wavefront inputs ----
    for (int e = t; e < T_ * T_; e += 256) {
        const int r = e >> 6, c = e & 63;
        SA[r][c] = dp[(size_t)(r0 + r) * L_ + r0 + c];   // tile (I,I)
        SB[r][c] = dp[(size_t)(q0 + r) * L_ + q0 + c];   // tile (J,J)
        const size_t gi = (size_t)(r0 + r) * L_ + q0 + c;
        epl[r][c] = ep[gi];
        mkb[r][c] = mask_bit(mode, pmW, pm8, pm16, pmf, gi) ? 1 : 0;
    }
    if (t < T_) {
        euI[t] = e_unp[(size_t)b * L_ + r0 + t];
        euJ[t] = e_unp[(size_t)b * L_ + q0 + t];
        rowB[t] = dp[(size_t)(r0 + T_) * L_ + q0 + t];   // dp[(I+1)T][j]
        colL[t] = dp[(size_t)(r0 + t) * L_ + q0 - 1];    // dp[i][JT-1]
    }
    if (t == 0) cornerS = (d >= 2) ? dp[(size_t)(r0 + T_) * L_ + q0 - 1] : 0.0f;
    __syncthreads();

    // ---- intra-tile wavefront: m = tj - ti ----
    const int cell = t >> 2, sub = t & 3;
    for (int m = -(T_ - 1); m <= T_ - 1; ++m) {
        const int am = m < 0 ? -m : m;
        if (cell < T_ - am) {
            const int ti = (m < 0) ? cell - m : cell;
            const int tj = ti + m;
            const int span = d * T_ + m;                  // j - i
            float mv = INFV; int km = 0;
            for (int tk = ti + sub; tk < T_; tk += 4) {   // left: k = r0+tk
                const float dk1j = (tk < T_ - 1) ? Ct[tk + 1][tj] : rowB[tj];
                const float v = SA[ti][tk] + dk1j;
                if (v < mv) { mv = v; km = r0 + tk; }
            }
            for (int tk = sub; tk < tj; tk += 4) {        // right: k = q0+tk
                const float v = Ct[ti][tk] + SB[tk + 1][tj];
                if (v < mv) { mv = v; km = q0 + tk; }
            }
            for (int off = 1; off < 4; off <<= 1) {       // lex (v,k) reduce
                const float ov = __shfl_xor(mv, off, 4);
                const int   ok = __shfl_xor(km, off, 4);
                if (ov < mv || (ov == mv && ok < km)) { mv = ov; km = ok; }
            }
            if (sub == 0) {
                const float bvv = accv[ti][tj]; const int bvk = acck[ti][tj];
                if (bvv < mv || (bvv == mv && bvk < km)) { mv = bvv; km = bvk; }
                const float c0 = ((ti < T_ - 1) ? Ct[ti + 1][tj] : rowB[tj]) + euI[ti];
                const float c1 = ((tj > 0) ? Ct[ti][tj - 1] : colL[ti]) + euJ[tj];
                float inner;
                if (span == 1)          inner = 0.0f;
                else if (ti < T_ - 1)   inner = (tj > 0) ? Ct[ti + 1][tj - 1] : colL[ti + 1];
                else                    inner = (tj > 0) ? rowB[tj - 1] : cornerS;
                const float c2 = inner + epl[ti][tj];
                const bool pok = mkb[ti][tj] && (span > 4);
                float best = c0; int bv = 0;
                if (c1 < best)        { best = c1; bv = 1; }
                if (pok && c2 < best) { best = c2; bv = 2; }
                if (mv < best)        { best = mv; bv = km + 3; }
                Ct[ti][tj] = best;
                bp[ti][tj] = (unsigned short)bv;
            }
        }
        __syncthreads();
    }

    // ---- writeback ----
    for (int e = t; e < T_ * T_; e += 256) {
        const int r = e >> 6, c = e & 63;
        const size_t gi = (size_t)(r0 + r) * L_ + q0 + c;
        dp[gi] = Ct[r][c];
        ptr[gi] = bp[r][c];
    }

    // ---- fused backtrace on final step (I=0, J=NT-1) ----
    if (do_bt) {
        int* res = out + (size_t)b * L_;
        for (int idx = t; idx < L_; idx += 256) res[idx] = -1;
        __syncthreads();
        if (t == 0) {
            int sp = 1; sti[0] = 0; stj[0] = L_ - 1;
            while (sp > 0) {
                --sp;
                const int i = sti[sp], j = stj[sp];
                if (i < j) {
                    int p;
                    if (i >= r0 && i < r0 + T_ && j >= q0 && j < q0 + T_)
                        p = bp[i - r0][j - q0];           // own tile: from LDS
                    else
                        p = ptr[(size_t)i * L_ + j];      // earlier launches
                    if (p == 0)      { sti[sp] = i + 1; stj[sp] = j;     ++sp; }
                    else if (p == 1) { sti[sp] = i;     stj[sp] = j - 1; ++sp; }
                    else if (p == 2) {
                        res[i] = j; res[j] = i;
                        if (i + 1 <= j - 1) { sti[sp] = i + 1; stj[sp] = j - 1; ++sp; }
                    } else {
                        const int k = p - 3;
                        sti[sp] = i;     stj[sp] = k; ++sp;   // pushed first
                        sti[sp] = k + 1; stj[sp] = j; ++sp;   // popped first
                    }
                }
            }
        }
    }
}

extern "C" void kernel_launch(void* const* d_in, const int* in_sizes, int n_in,
                              void* d_out, int out_size, void* d_ws, size_t ws_size,
                              hipStream_t stream) {
    const float* e_pair = (const float*)d_in[0];
    const float* e_unp  = (const float*)d_in[1];
    const unsigned int* pm = (const unsigned int*)d_in[2];
    const int B = in_sizes[1] / L_;
    int* out = (int*)d_out;

    // ws layout: [flags: 256B] [dp: B*L*L f32] [ptr: B*L*L u16]
    unsigned int* flags = (unsigned int*)d_ws;
    float* dp_ws = (float*)((char*)d_ws + 256);
    unsigned short* ptr_ws = (unsigned short*)(dp_ws + (size_t)B * NBUF);

    const int n32 = in_sizes[2] / 4;
    fd_mask_probe<<<dim3(1), dim3(1024), 0, stream>>>(pm, n32, flags);
    fd_diag<<<dim3(B * NT_), dim3(256), 0, stream>>>(e_pair, e_unp, pm, flags,
                                                     dp_ws, ptr_ws);
    for (int d = 1; d < NT_; ++d) {
        const int nI = NT_ - d;
        fd_step<<<dim3(B * nI), dim3(256), 0, stream>>>(e_pair, e_unp, pm, flags,
                                                        dp_ws, ptr_ws, out,
                                                        d, nI, d == NT_ - 1 ? 1 : 0);
    }
}